// Round 4
// baseline (440.804 us; speedup 1.0000x reference)
//
#include <hip/hip_runtime.h>
#include <math.h>

// Problem constants
#define B_SZ 2
#define SEQ 2048
#define DMODEL 1024
#define NH 16
#define DK 64
#define NQKV 3072
#define M_ROWS 4096

#define NEG_BIG (-3.0e38f)

typedef short short8 __attribute__((ext_vector_type(8)));
typedef float v4f __attribute__((ext_vector_type(4)));
typedef unsigned short ushort_t;

__device__ inline ushort_t f2bf(float f) {
    unsigned u = __float_as_uint(f);
    u += 0x7fffu + ((u >> 16) & 1u);   // RNE
    return (ushort_t)(u >> 16);
}

// ---------------------------------------------------------------------------
// Kernel 0a: fp32 -> bf16 convert (vector of 4)
// ---------------------------------------------------------------------------
__global__ __launch_bounds__(256) void cvt_bf16_kernel(
    const float* __restrict__ src, ushort_t* __restrict__ dst, int n4)
{
    int i = blockIdx.x * 256 + threadIdx.x;
    if (i < n4) {
        float4 v = reinterpret_cast<const float4*>(src)[i];
        ushort4 r;
        r.x = f2bf(v.x); r.y = f2bf(v.y); r.z = f2bf(v.z); r.w = f2bf(v.w);
        reinterpret_cast<ushort4*>(dst)[i] = r;
    }
}

// ---------------------------------------------------------------------------
// Kernel 0b: extract RoPE cos/sin tables from the [2048,64,64] matrix buffer.
// cosT[p*64+d] = R[p][d][d];  sinT[p*64+d] = +-R[p][d|1][d&~1]
// so that rotated v' = cosT[d]*v + sinT[d]*pair(v), pair = shfl_xor(v,1).
// ---------------------------------------------------------------------------
__global__ __launch_bounds__(256) void rope_table_kernel(
    const float* __restrict__ rope, float* __restrict__ cosT, float* __restrict__ sinT)
{
    int i = blockIdx.x * 256 + threadIdx.x;   // [0, 2048*64)
    int p = i >> 6, d = i & 63;
    const float* Rp = rope + (size_t)p * 4096;
    float c = Rp[d * 64 + d];
    float s = Rp[(d | 1) * 64 + (d & ~1)];
    cosT[i] = c;
    sinT[i] = (d & 1) ? s : -s;
}

// ---------------------------------------------------------------------------
// Kernel 1: QKV projection + RoPE epilogue -> Q/K/V bf16 [B,H,S,DK]
// MFMA 128x128 tile, BK=32, 4 waves 2x2. Layouts (verified m89/m91):
//   A/B operand: idx = lane&15, k = (lane>>4)*8 + j
//   C/D:         col = lane&15 (B idx), row = (lane>>4)*4 + reg (A idx)
// ---------------------------------------------------------------------------
__global__ __launch_bounds__(256) void qkv_mfma_kernel(
    const ushort_t* __restrict__ xb,   // [4096,1024] bf16
    const ushort_t* __restrict__ Wab,  // [3072,1024] bf16
    const float* __restrict__ cosT, const float* __restrict__ sinT,
    const int* __restrict__ tpos,
    ushort_t* __restrict__ Qb, ushort_t* __restrict__ Kb, ushort_t* __restrict__ Vb)
{
    __shared__ ushort_t As[128][40];   // [m][k] pad 32->40
    __shared__ ushort_t Bs[128][40];   // [n][k]

    const int tid = threadIdx.x;
    const int w = tid >> 6, lane = tid & 63;
    const int lm = lane & 15, g = lane >> 4, lk8 = g * 8;
    const int wm = (w >> 1) * 64, wn = (w & 1) * 64;
    const int m0 = blockIdx.y * 128, n0 = blockIdx.x * 128;

    v4f acc[4][4] = {};

    for (int k0 = 0; k0 < DMODEL; k0 += 32) {
        short8 a[2], b[2];
#pragma unroll
        for (int rep = 0; rep < 2; ++rep) {
            const int c = tid + 256 * rep;
            const int r = c >> 2, q8 = (c & 3) * 8;
            a[rep] = *reinterpret_cast<const short8*>(&xb [(size_t)(m0 + r) * DMODEL + k0 + q8]);
            b[rep] = *reinterpret_cast<const short8*>(&Wab[(size_t)(n0 + r) * DMODEL + k0 + q8]);
        }
        __syncthreads();
#pragma unroll
        for (int rep = 0; rep < 2; ++rep) {
            const int c = tid + 256 * rep;
            const int r = c >> 2, q8 = (c & 3) * 8;
            *reinterpret_cast<short8*>(&As[r][q8]) = a[rep];
            *reinterpret_cast<short8*>(&Bs[r][q8]) = b[rep];
        }
        __syncthreads();

        short8 af[4], bfr[4];
#pragma unroll
        for (int mf = 0; mf < 4; ++mf) af[mf]  = *reinterpret_cast<const short8*>(&As[wm + mf * 16 + lm][lk8]);
#pragma unroll
        for (int nf = 0; nf < 4; ++nf) bfr[nf] = *reinterpret_cast<const short8*>(&Bs[wn + nf * 16 + lm][lk8]);
#pragma unroll
        for (int mf = 0; mf < 4; ++mf)
#pragma unroll
            for (int nf = 0; nf < 4; ++nf)
                acc[mf][nf] = __builtin_amdgcn_mfma_f32_16x16x32_bf16(af[mf], bfr[nf], acc[mf][nf], 0, 0, 0);
    }

    const int which = n0 >> 10;            // 0=Q,1=K,2=V (block-uniform)
    ushort_t* buf = (which == 0) ? Qb : ((which == 1) ? Kb : Vb);
    const int nbase = n0 + wn;

#pragma unroll
    for (int mf = 0; mf < 4; ++mf) {
#pragma unroll
        for (int reg = 0; reg < 4; ++reg) {
            const int m = m0 + wm + mf * 16 + g * 4 + reg;
            const int bb = m >> 11, s = m & 2047;
            const int p = tpos[s];
#pragma unroll
            for (int nf = 0; nf < 4; ++nf) {
                const int n = nbase + nf * 16 + lm;
                const int h = (n >> 6) & 15;
                const int d = n & 63;
                float v = acc[mf][nf][reg];
                if (which < 2) {
                    const float pr = __shfl_xor(v, 1, 64);
                    v = cosT[p * 64 + d] * v + sinT[p * 64 + d] * pr;
                }
                buf[(((size_t)bb * NH + h) * SEQ + s) * DK + d] = f2bf(v);
            }
        }
    }
}

// ---------------------------------------------------------------------------
// Kernel 1b: transpose V [B,H,S,DK] -> Vt [B,H,DK,S] (bf16)
// ---------------------------------------------------------------------------
__global__ __launch_bounds__(256) void transpose_v_kernel(
    const ushort_t* __restrict__ Vb, ushort_t* __restrict__ Vtb)
{
    __shared__ ushort_t t[64][72];
    const int tid = threadIdx.x;
    const int s0 = blockIdx.x * 64;
    const int hb = blockIdx.y;                 // b*NH+h
    const size_t base = (size_t)hb * SEQ * DK;
#pragma unroll
    for (int r = 0; r < 2; ++r) {
        const int c = tid + 256 * r;
        const int row = c >> 3, col8 = (c & 7) * 8;
        short8 v = *reinterpret_cast<const short8*>(&Vb[base + (size_t)(s0 + row) * DK + col8]);
#pragma unroll
        for (int j = 0; j < 8; ++j) t[col8 + j][row] = (ushort_t)v[j];
    }
    __syncthreads();
#pragma unroll
    for (int r = 0; r < 2; ++r) {
        const int c = tid + 256 * r;
        const int drow = c >> 3, s8 = (c & 7) * 8;
        short8 v = *reinterpret_cast<const short8*>(&t[drow][s8]);
        *reinterpret_cast<short8*>(&Vtb[base + (size_t)drow * SEQ + s0 + s8]) = v;
    }
}

// ---------------------------------------------------------------------------
// Kernel 2: flash attention — barrier-free, LDS-free.
// Wave w owns q rows [q0+16w, q0+16w+16). Computes S^T = K Q^T (A=K, B=Q),
// softmax over kv (in-lane regs + 2 shfls), P^T -> PV B-operand via shfl
// permutation, O^T += V^T P^T with V^T fragments straight from global.
// ---------------------------------------------------------------------------
__global__ __launch_bounds__(256) void attn_mfma_kernel(
    const ushort_t* __restrict__ Qb, const ushort_t* __restrict__ Kb,
    const ushort_t* __restrict__ Vtb, ushort_t* __restrict__ attb)
{
    const int tid = threadIdx.x;
    const int w = tid >> 6, lane = tid & 63;
    const int lm = lane & 15, g = lane >> 4, lk8 = g * 8;

    const int it = (SEQ / 64 - 1) - blockIdx.x;   // heavy tiles first
    const int h = blockIdx.y, b = blockIdx.z;
    const size_t ho = ((size_t)b * NH + h) * SEQ * DK;
    const ushort_t* Qh = Qb + ho;
    const ushort_t* Kh = Kb + ho;
    const ushort_t* Vth = Vtb + ho;               // [DK][SEQ]

    const int q0 = it * 64;
    const int qrow = q0 + w * 16 + lm;

    short8 qf[2];
    qf[0] = *reinterpret_cast<const short8*>(&Qh[(size_t)qrow * DK + lk8]);
    qf[1] = *reinterpret_cast<const short8*>(&Qh[(size_t)qrow * DK + 32 + lk8]);

    float m_i = NEG_BIG, l_i = 0.f;
    v4f Oa[4] = {};   // O^T tiles: row d = df*16+g*4+reg, col q = lm

    const int tsel = g >> 1;
    const int srcA = ((g & 1) * 2) * 16 + lm;  // source lanes for B-frag dwords
    const int srcB = srcA + 16;

    for (int jt = 0; jt <= it; ++jt) {
        const int c0 = jt * 64;

        // S^T = K Q^T  (A=K rows=kv, B=Q cols=q)
        v4f sacc[4] = {};
#pragma unroll
        for (int nf = 0; nf < 4; ++nf) {
            const short8 kf0 = *reinterpret_cast<const short8*>(&Kh[(size_t)(c0 + nf * 16 + lm) * DK + lk8]);
            const short8 kf1 = *reinterpret_cast<const short8*>(&Kh[(size_t)(c0 + nf * 16 + lm) * DK + 32 + lk8]);
            sacc[nf] = __builtin_amdgcn_mfma_f32_16x16x32_bf16(kf0, qf[0], sacc[nf], 0, 0, 0);
            sacc[nf] = __builtin_amdgcn_mfma_f32_16x16x32_bf16(kf1, qf[1], sacc[nf], 0, 0, 0);
        }

        // scale + causal mask (rows = kv, col = qrow); diagonal tile only
        if (jt == it) {
#pragma unroll
            for (int nf = 0; nf < 4; ++nf)
#pragma unroll
                for (int reg = 0; reg < 4; ++reg) {
                    const int kv = c0 + nf * 16 + g * 4 + reg;
                    const float sv = sacc[nf][reg] * 0.125f;
                    sacc[nf][reg] = (kv > qrow) ? NEG_BIG : sv;
                }
        } else {
#pragma unroll
            for (int nf = 0; nf < 4; ++nf)
#pragma unroll
                for (int reg = 0; reg < 4; ++reg) sacc[nf][reg] *= 0.125f;
        }

        // online softmax over kv: local 16 regs, then lanes ^16, ^32 (g-dim)
        float mloc = sacc[0][0];
#pragma unroll
        for (int nf = 0; nf < 4; ++nf)
#pragma unroll
            for (int reg = 0; reg < 4; ++reg) mloc = fmaxf(mloc, sacc[nf][reg]);
        mloc = fmaxf(mloc, __shfl_xor(mloc, 16, 64));
        mloc = fmaxf(mloc, __shfl_xor(mloc, 32, 64));
        const float mnew = fmaxf(m_i, mloc);
        const float alpha = __expf(m_i - mnew);
        float rs = 0.f;
#pragma unroll
        for (int nf = 0; nf < 4; ++nf)
#pragma unroll
            for (int reg = 0; reg < 4; ++reg) {
                const float p = __expf(sacc[nf][reg] - mnew);
                sacc[nf][reg] = p;
                rs += p;
            }
        rs += __shfl_xor(rs, 16, 64);
        rs += __shfl_xor(rs, 32, 64);
        l_i = l_i * alpha + rs;
        m_i = mnew;
#pragma unroll
        for (int df = 0; df < 4; ++df)
#pragma unroll
            for (int reg = 0; reg < 4; ++reg) Oa[df][reg] *= alpha;

        // pack P tiles: pk[t][0]=regs(0,1), pk[t][1]=regs(2,3) as bf16x2
        unsigned pk[4][2];
#pragma unroll
        for (int t = 0; t < 4; ++t) {
            pk[t][0] = (unsigned)f2bf(sacc[t][0]) | ((unsigned)f2bf(sacc[t][1]) << 16);
            pk[t][1] = (unsigned)f2bf(sacc[t][2]) | ((unsigned)f2bf(sacc[t][3]) << 16);
        }

        // PV: O^T += V^T * P^T, two k=32 MFMAs (kc) per 64-kv tile
#pragma unroll
        for (int kc = 0; kc < 2; ++kc) {
            const int tA = kc * 2, tB = kc * 2 + 1;
            const unsigned d0a = (unsigned)__shfl((int)pk[tA][0], srcA, 64);
            const unsigned d0b = (unsigned)__shfl((int)pk[tB][0], srcA, 64);
            const unsigned d1a = (unsigned)__shfl((int)pk[tA][1], srcA, 64);
            const unsigned d1b = (unsigned)__shfl((int)pk[tB][1], srcA, 64);
            const unsigned d2a = (unsigned)__shfl((int)pk[tA][0], srcB, 64);
            const unsigned d2b = (unsigned)__shfl((int)pk[tB][0], srcB, 64);
            const unsigned d3a = (unsigned)__shfl((int)pk[tA][1], srcB, 64);
            const unsigned d3b = (unsigned)__shfl((int)pk[tB][1], srcB, 64);
            union { uint4 u; short8 s; } cv;
            cv.u.x = tsel ? d0b : d0a;
            cv.u.y = tsel ? d1b : d1a;
            cv.u.z = tsel ? d2b : d2a;
            cv.u.w = tsel ? d3b : d3a;
            const short8 pf = cv.s;
#pragma unroll
            for (int df = 0; df < 4; ++df) {
                const short8 vf = *reinterpret_cast<const short8*>(
                    &Vth[(size_t)(df * 16 + lm) * SEQ + c0 + kc * 32 + lk8]);
                Oa[df] = __builtin_amdgcn_mfma_f32_16x16x32_bf16(vf, pf, Oa[df], 0, 0, 0);
            }
        }
    }

    // epilogue: normalize, store bf16 att[b][s][h*64+d]; d = df*16+g*4+reg
    const float inv = 1.0f / l_i;
#pragma unroll
    for (int df = 0; df < 4; ++df) {
        const unsigned lo = (unsigned)f2bf(Oa[df][0] * inv) | ((unsigned)f2bf(Oa[df][1] * inv) << 16);
        const unsigned hi = (unsigned)f2bf(Oa[df][2] * inv) | ((unsigned)f2bf(Oa[df][3] * inv) << 16);
        uint2 st; st.x = lo; st.y = hi;
        *reinterpret_cast<uint2*>(
            &attb[((size_t)b * SEQ + qrow) * DMODEL + h * DK + df * 16 + g * 4]) = st;
    }
}

// ---------------------------------------------------------------------------
// Kernel 3: output projection, bf16 MFMA, fp32 out.
// ---------------------------------------------------------------------------
__global__ __launch_bounds__(256) void out_mfma_kernel(
    const ushort_t* __restrict__ attb,  // [4096,1024] bf16
    const ushort_t* __restrict__ Wob,   // [1024,1024] bf16
    float* __restrict__ out)            // [4096,1024] fp32
{
    __shared__ ushort_t As[128][40];
    __shared__ ushort_t Bs[128][40];

    const int tid = threadIdx.x;
    const int w = tid >> 6, lane = tid & 63;
    const int lm = lane & 15, g = lane >> 4, lk8 = g * 8;
    const int wm = (w >> 1) * 64, wn = (w & 1) * 64;
    const int m0 = blockIdx.y * 128, n0 = blockIdx.x * 128;

    v4f acc[4][4] = {};

    for (int k0 = 0; k0 < DMODEL; k0 += 32) {
        short8 a[2], b[2];
#pragma unroll
        for (int rep = 0; rep < 2; ++rep) {
            const int c = tid + 256 * rep;
            const int r = c >> 2, q8 = (c & 3) * 8;
            a[rep] = *reinterpret_cast<const short8*>(&attb[(size_t)(m0 + r) * DMODEL + k0 + q8]);
            b[rep] = *reinterpret_cast<const short8*>(&Wob [(size_t)(n0 + r) * DMODEL + k0 + q8]);
        }
        __syncthreads();
#pragma unroll
        for (int rep = 0; rep < 2; ++rep) {
            const int c = tid + 256 * rep;
            const int r = c >> 2, q8 = (c & 3) * 8;
            *reinterpret_cast<short8*>(&As[r][q8]) = a[rep];
            *reinterpret_cast<short8*>(&Bs[r][q8]) = b[rep];
        }
        __syncthreads();

        short8 af[4], bfr[4];
#pragma unroll
        for (int mf = 0; mf < 4; ++mf) af[mf]  = *reinterpret_cast<const short8*>(&As[wm + mf * 16 + lm][lk8]);
#pragma unroll
        for (int nf = 0; nf < 4; ++nf) bfr[nf] = *reinterpret_cast<const short8*>(&Bs[wn + nf * 16 + lm][lk8]);
#pragma unroll
        for (int mf = 0; mf < 4; ++mf)
#pragma unroll
            for (int nf = 0; nf < 4; ++nf)
                acc[mf][nf] = __builtin_amdgcn_mfma_f32_16x16x32_bf16(af[mf], bfr[nf], acc[mf][nf], 0, 0, 0);
    }

#pragma unroll
    for (int mf = 0; mf < 4; ++mf)
#pragma unroll
        for (int reg = 0; reg < 4; ++reg) {
            const int m = m0 + wm + mf * 16 + g * 4 + reg;
#pragma unroll
            for (int nf = 0; nf < 4; ++nf) {
                const int n = n0 + wn + nf * 16 + lm;
                out[(size_t)m * DMODEL + n] = acc[mf][nf][reg];
            }
        }
}

// ---------------------------------------------------------------------------
extern "C" void kernel_launch(void* const* d_in, const int* in_sizes, int n_in,
                              void* d_out, int out_size, void* d_ws, size_t ws_size,
                              hipStream_t stream) {
    (void)in_sizes; (void)n_in; (void)out_size; (void)ws_size;

    const float* x    = (const float*)d_in[0];
    const float* Wa   = (const float*)d_in[1];
    const float* Wo   = (const float*)d_in[2];
    const float* rope = (const float*)d_in[3];
    const int*   tp   = (const int*)d_in[4];
    float* out = (float*)d_out;

    char* ws = (char*)d_ws;
    ushort_t* xb   = (ushort_t*)(ws);                       // 8 MB
    ushort_t* Wab  = (ushort_t*)(ws + (8u << 20));          // 6 MB
    ushort_t* Wob  = (ushort_t*)(ws + (14u << 20));         // 2 MB
    float*    cosT = (float*)   (ws + (16u << 20));         // 0.5 MB
    float*    sinT = (float*)   (ws + (16u << 20) + (512u << 10));
    ushort_t* Qb   = (ushort_t*)(ws + (17u << 20));         // 8 MB
    ushort_t* Kb   = (ushort_t*)(ws + (25u << 20));         // 8 MB
    ushort_t* Vb   = (ushort_t*)(ws + (33u << 20));         // 8 MB
    ushort_t* Vtb  = (ushort_t*)(ws + (41u << 20));         // 8 MB
    ushort_t* attb = (ushort_t*)(ws + (49u << 20));         // 8 MB

    dim3 blk(256);
    cvt_bf16_kernel<<<dim3((M_ROWS * DMODEL / 4) / 256), blk, 0, stream>>>(x,  xb,  M_ROWS * DMODEL / 4);
    cvt_bf16_kernel<<<dim3((NQKV  * DMODEL / 4) / 256), blk, 0, stream>>>(Wa, Wab, NQKV  * DMODEL / 4);
    cvt_bf16_kernel<<<dim3((DMODEL * DMODEL / 4) / 256), blk, 0, stream>>>(Wo, Wob, DMODEL * DMODEL / 4);
    rope_table_kernel<<<dim3(SEQ * DK / 256), blk, 0, stream>>>(rope, cosT, sinT);

    qkv_mfma_kernel<<<dim3(NQKV / 128, M_ROWS / 128), blk, 0, stream>>>(
        xb, Wab, cosT, sinT, tp, Qb, Kb, Vb);
    transpose_v_kernel<<<dim3(SEQ / 64, B_SZ * NH), blk, 0, stream>>>(Vb, Vtb);
    attn_mfma_kernel<<<dim3(SEQ / 64, NH, B_SZ), blk, 0, stream>>>(Qb, Kb, Vtb, attb);
    out_mfma_kernel<<<dim3(DMODEL / 128, M_ROWS / 128), blk, 0, stream>>>(attb, Wob, out);
}

// Round 5
// 267.920 us; speedup vs baseline: 1.6453x; 1.6453x over previous
//
#include <hip/hip_runtime.h>
#include <math.h>

// Problem constants
#define B_SZ 2
#define SEQ 2048
#define DMODEL 1024
#define NH 16
#define DK 64
#define NQKV 3072
#define M_ROWS 4096

#define NEG_BIG (-3.0e38f)

typedef short short8 __attribute__((ext_vector_type(8)));
typedef float v4f __attribute__((ext_vector_type(4)));
typedef unsigned short ushort_t;

__device__ inline ushort_t f2bf(float f) {
    unsigned u = __float_as_uint(f);
    u += 0x7fffu + ((u >> 16) & 1u);   // RNE
    return (ushort_t)(u >> 16);
}

// ---------------------------------------------------------------------------
// Kernel 0a: fp32 -> bf16 convert (vector of 4)
// ---------------------------------------------------------------------------
__global__ __launch_bounds__(256) void cvt_bf16_kernel(
    const float* __restrict__ src, ushort_t* __restrict__ dst, int n4)
{
    int i = blockIdx.x * 256 + threadIdx.x;
    if (i < n4) {
        float4 v = reinterpret_cast<const float4*>(src)[i];
        ushort4 r;
        r.x = f2bf(v.x); r.y = f2bf(v.y); r.z = f2bf(v.z); r.w = f2bf(v.w);
        reinterpret_cast<ushort4*>(dst)[i] = r;
    }
}

// ---------------------------------------------------------------------------
// Kernel 0b: extract RoPE cos/sin tables from the [2048,64,64] matrix buffer.
// cosT[p*64+d] = R[p][d][d];  sinT[p*64+d] = +-R[p][d|1][d&~1]
// so that rotated v' = cosT[d]*v + sinT[d]*pair(v), pair = shfl_xor(v,1).
// ---------------------------------------------------------------------------
__global__ __launch_bounds__(256) void rope_table_kernel(
    const float* __restrict__ rope, float* __restrict__ cosT, float* __restrict__ sinT)
{
    int i = blockIdx.x * 256 + threadIdx.x;   // [0, 2048*64)
    int p = i >> 6, d = i & 63;
    const float* Rp = rope + (size_t)p * 4096;
    float c = Rp[d * 64 + d];
    float s = Rp[(d | 1) * 64 + (d & ~1)];
    cosT[i] = c;
    sinT[i] = (d & 1) ? s : -s;
}

// ---------------------------------------------------------------------------
// Kernel 1: QKV projection + RoPE epilogue -> Q/K/V bf16 [B,H,S,DK]
// MFMA 128x128 tile, BK=32, 4 waves 2x2. Layouts (verified m89/m91):
//   A/B operand: idx = lane&15, k = (lane>>4)*8 + j
//   C/D:         col = lane&15 (B idx), row = (lane>>4)*4 + reg (A idx)
// ---------------------------------------------------------------------------
__global__ __launch_bounds__(256) void qkv_mfma_kernel(
    const ushort_t* __restrict__ xb,   // [4096,1024] bf16
    const ushort_t* __restrict__ Wab,  // [3072,1024] bf16
    const float* __restrict__ cosT, const float* __restrict__ sinT,
    const int* __restrict__ tpos,
    ushort_t* __restrict__ Qb, ushort_t* __restrict__ Kb, ushort_t* __restrict__ Vb)
{
    __shared__ ushort_t As[128][40];   // [m][k] pad 32->40
    __shared__ ushort_t Bs[128][40];   // [n][k]

    const int tid = threadIdx.x;
    const int w = tid >> 6, lane = tid & 63;
    const int lm = lane & 15, g = lane >> 4, lk8 = g * 8;
    const int wm = (w >> 1) * 64, wn = (w & 1) * 64;
    const int m0 = blockIdx.y * 128, n0 = blockIdx.x * 128;

    v4f acc[4][4] = {};

    for (int k0 = 0; k0 < DMODEL; k0 += 32) {
        short8 a[2], b[2];
#pragma unroll
        for (int rep = 0; rep < 2; ++rep) {
            const int c = tid + 256 * rep;
            const int r = c >> 2, q8 = (c & 3) * 8;
            a[rep] = *reinterpret_cast<const short8*>(&xb [(size_t)(m0 + r) * DMODEL + k0 + q8]);
            b[rep] = *reinterpret_cast<const short8*>(&Wab[(size_t)(n0 + r) * DMODEL + k0 + q8]);
        }
        __syncthreads();
#pragma unroll
        for (int rep = 0; rep < 2; ++rep) {
            const int c = tid + 256 * rep;
            const int r = c >> 2, q8 = (c & 3) * 8;
            *reinterpret_cast<short8*>(&As[r][q8]) = a[rep];
            *reinterpret_cast<short8*>(&Bs[r][q8]) = b[rep];
        }
        __syncthreads();

        short8 af[4], bfr[4];
#pragma unroll
        for (int mf = 0; mf < 4; ++mf) af[mf]  = *reinterpret_cast<const short8*>(&As[wm + mf * 16 + lm][lk8]);
#pragma unroll
        for (int nf = 0; nf < 4; ++nf) bfr[nf] = *reinterpret_cast<const short8*>(&Bs[wn + nf * 16 + lm][lk8]);
#pragma unroll
        for (int mf = 0; mf < 4; ++mf)
#pragma unroll
            for (int nf = 0; nf < 4; ++nf)
                acc[mf][nf] = __builtin_amdgcn_mfma_f32_16x16x32_bf16(af[mf], bfr[nf], acc[mf][nf], 0, 0, 0);
    }

    const int which = n0 >> 10;            // 0=Q,1=K,2=V (block-uniform)
    ushort_t* buf = (which == 0) ? Qb : ((which == 1) ? Kb : Vb);
    const int nbase = n0 + wn;

#pragma unroll
    for (int mf = 0; mf < 4; ++mf) {
#pragma unroll
        for (int reg = 0; reg < 4; ++reg) {
            const int m = m0 + wm + mf * 16 + g * 4 + reg;
            const int bb = m >> 11, s = m & 2047;
            const int p = tpos[s];
#pragma unroll
            for (int nf = 0; nf < 4; ++nf) {
                const int n = nbase + nf * 16 + lm;
                const int h = (n >> 6) & 15;
                const int d = n & 63;
                float v = acc[mf][nf][reg];
                if (which < 2) {
                    const float pr = __shfl_xor(v, 1, 64);
                    v = cosT[p * 64 + d] * v + sinT[p * 64 + d] * pr;
                }
                buf[(((size_t)bb * NH + h) * SEQ + s) * DK + d] = f2bf(v);
            }
        }
    }
}

// ---------------------------------------------------------------------------
// Kernel 1b: transpose V [B,H,S,DK] -> Vt [B,H,DK,S] (bf16)
// ---------------------------------------------------------------------------
__global__ __launch_bounds__(256) void transpose_v_kernel(
    const ushort_t* __restrict__ Vb, ushort_t* __restrict__ Vtb)
{
    __shared__ ushort_t t[64][72];
    const int tid = threadIdx.x;
    const int s0 = blockIdx.x * 64;
    const int hb = blockIdx.y;                 // b*NH+h
    const size_t base = (size_t)hb * SEQ * DK;
#pragma unroll
    for (int r = 0; r < 2; ++r) {
        const int c = tid + 256 * r;
        const int row = c >> 3, col8 = (c & 7) * 8;
        short8 v = *reinterpret_cast<const short8*>(&Vb[base + (size_t)(s0 + row) * DK + col8]);
#pragma unroll
        for (int j = 0; j < 8; ++j) t[col8 + j][row] = (ushort_t)v[j];
    }
    __syncthreads();
#pragma unroll
    for (int r = 0; r < 2; ++r) {
        const int c = tid + 256 * r;
        const int drow = c >> 3, s8 = (c & 7) * 8;
        short8 v = *reinterpret_cast<const short8*>(&t[drow][s8]);
        *reinterpret_cast<short8*>(&Vtb[base + (size_t)drow * SEQ + s0 + s8]) = v;
    }
}

// ---------------------------------------------------------------------------
// Kernel 2: flash attention v3.
//  - S^T = K Q^T formulation: softmax reduce = in-lane + 2 shfls (verified R4)
//  - K, V^T staged cooperatively in LDS (b128, pad-72 rows), 2 barriers/tile
//  - P^T -> B-operand via WAVE-PRIVATE LDS rows: ds_write_b64 packed (regs =
//    4 consecutive kv), ds_read_b128; no barrier, no bpermute
//  - balanced grid: block u handles q-tiles u and 31-u (33 kv-iters each)
// ---------------------------------------------------------------------------
__global__ __launch_bounds__(256) void attn_mfma_kernel(
    const ushort_t* __restrict__ Qb, const ushort_t* __restrict__ Kb,
    const ushort_t* __restrict__ Vtb, ushort_t* __restrict__ attb)
{
    __shared__ ushort_t Ks[64][72];    // [kv][d]
    __shared__ ushort_t Vs[64][72];    // [d][kv]  (V^T)
    __shared__ ushort_t Ps[64][72];    // [q][kv]; wave w owns rows [16w,16w+16)

    const int tid = threadIdx.x;
    const int w = tid >> 6, lane = tid & 63;
    const int lm = lane & 15, g = lane >> 4, lk8 = g * 8;

    const int u = blockIdx.x;                     // 0..15
    const int h = blockIdx.y, b = blockIdx.z;
    const size_t ho = ((size_t)b * NH + h) * SEQ * DK;
    const ushort_t* Qh = Qb + ho;
    const ushort_t* Kh = Kb + ho;
    const ushort_t* Vth = Vtb + ho;               // [DK][SEQ]

#pragma unroll
    for (int half = 0; half < 2; ++half) {
        const int it = half ? (31 - u) : u;
        const int q0 = it * 64;
        const int qrow = q0 + w * 16 + lm;

        short8 qf0 = *reinterpret_cast<const short8*>(&Qh[(size_t)qrow * DK + lk8]);
        short8 qf1 = *reinterpret_cast<const short8*>(&Qh[(size_t)qrow * DK + 32 + lk8]);

        float m_i = NEG_BIG, l_i = 0.f;
        v4f Oa[4] = {};   // O^T: row d = df*16+g*4+reg, col q = lm

        for (int jt = 0; jt <= it; ++jt) {
            const int c0 = jt * 64;

            // cooperative stage of K [kv][d] and V^T [d][kv]; 512 chunks each
            short8 kreg[2], vreg[2];
            int rr[2], cc8[2];
#pragma unroll
            for (int rep = 0; rep < 2; ++rep) {
                const int c = tid + 256 * rep;
                rr[rep] = c >> 3; cc8[rep] = (c & 7) * 8;
                kreg[rep] = *reinterpret_cast<const short8*>(&Kh[(size_t)(c0 + rr[rep]) * DK + cc8[rep]]);
                vreg[rep] = *reinterpret_cast<const short8*>(&Vth[(size_t)rr[rep] * SEQ + c0 + cc8[rep]]);
            }
            __syncthreads();   // prior iter's frag reads of Ks/Vs done
#pragma unroll
            for (int rep = 0; rep < 2; ++rep) {
                *reinterpret_cast<short8*>(&Ks[rr[rep]][cc8[rep]]) = kreg[rep];
                *reinterpret_cast<short8*>(&Vs[rr[rep]][cc8[rep]]) = vreg[rep];
            }
            __syncthreads();   // staged

            // S^T = K Q^T  (A = K rows kv, B = Q cols q)
            v4f sacc[4] = {};
#pragma unroll
            for (int nf = 0; nf < 4; ++nf) {
                const short8 kf0 = *reinterpret_cast<const short8*>(&Ks[nf * 16 + lm][lk8]);
                const short8 kf1 = *reinterpret_cast<const short8*>(&Ks[nf * 16 + lm][32 + lk8]);
                sacc[nf] = __builtin_amdgcn_mfma_f32_16x16x32_bf16(kf0, qf0, sacc[nf], 0, 0, 0);
                sacc[nf] = __builtin_amdgcn_mfma_f32_16x16x32_bf16(kf1, qf1, sacc[nf], 0, 0, 0);
            }

            // scale + causal mask (rows = kv, col = qrow); diagonal tile only
            if (jt == it) {
#pragma unroll
                for (int nf = 0; nf < 4; ++nf)
#pragma unroll
                    for (int reg = 0; reg < 4; ++reg) {
                        const int kv = c0 + nf * 16 + g * 4 + reg;
                        const float sv = sacc[nf][reg] * 0.125f;
                        sacc[nf][reg] = (kv > qrow) ? NEG_BIG : sv;
                    }
            } else {
#pragma unroll
                for (int nf = 0; nf < 4; ++nf)
#pragma unroll
                    for (int reg = 0; reg < 4; ++reg) sacc[nf][reg] *= 0.125f;
            }

            // online softmax over kv: 16 in-lane values, then lanes ^16, ^32
            float mloc = sacc[0][0];
#pragma unroll
            for (int nf = 0; nf < 4; ++nf)
#pragma unroll
                for (int reg = 0; reg < 4; ++reg) mloc = fmaxf(mloc, sacc[nf][reg]);
            mloc = fmaxf(mloc, __shfl_xor(mloc, 16, 64));
            mloc = fmaxf(mloc, __shfl_xor(mloc, 32, 64));
            const float mnew = fmaxf(m_i, mloc);
            const float alpha = __expf(m_i - mnew);
            float rs = 0.f;
#pragma unroll
            for (int nf = 0; nf < 4; ++nf)
#pragma unroll
                for (int reg = 0; reg < 4; ++reg) {
                    const float p = __expf(sacc[nf][reg] - mnew);
                    sacc[nf][reg] = p;
                    rs += p;
                }
            rs += __shfl_xor(rs, 16, 64);
            rs += __shfl_xor(rs, 32, 64);
            l_i = l_i * alpha + rs;
            m_i = mnew;
#pragma unroll
            for (int df = 0; df < 4; ++df)
#pragma unroll
                for (int reg = 0; reg < 4; ++reg) Oa[df][reg] *= alpha;

            // P store: row q = w*16+lm (wave-private), cols kv; regs are 4
            // consecutive kv -> one b64 per frag. No barrier needed.
#pragma unroll
            for (int nf = 0; nf < 4; ++nf) {
                uint2 pp;
                pp.x = (unsigned)f2bf(sacc[nf][0]) | ((unsigned)f2bf(sacc[nf][1]) << 16);
                pp.y = (unsigned)f2bf(sacc[nf][2]) | ((unsigned)f2bf(sacc[nf][3]) << 16);
                *reinterpret_cast<uint2*>(&Ps[w * 16 + lm][nf * 16 + g * 4]) = pp;
            }

            // PV: O^T += V^T P^T ; A = Vs[d][kv], B = Ps[q][kv]
#pragma unroll
            for (int kc = 0; kc < 2; ++kc) {
                const short8 pf = *reinterpret_cast<const short8*>(&Ps[w * 16 + lm][kc * 32 + lk8]);
#pragma unroll
                for (int df = 0; df < 4; ++df) {
                    const short8 vf = *reinterpret_cast<const short8*>(&Vs[df * 16 + lm][kc * 32 + lk8]);
                    Oa[df] = __builtin_amdgcn_mfma_f32_16x16x32_bf16(vf, pf, Oa[df], 0, 0, 0);
                }
            }
        }

        // epilogue: normalize, store bf16 att[b][qrow][h*64+d]; d = df*16+g*4+reg
        const float inv = 1.0f / l_i;
#pragma unroll
        for (int df = 0; df < 4; ++df) {
            const unsigned lo = (unsigned)f2bf(Oa[df][0] * inv) | ((unsigned)f2bf(Oa[df][1] * inv) << 16);
            const unsigned hi = (unsigned)f2bf(Oa[df][2] * inv) | ((unsigned)f2bf(Oa[df][3] * inv) << 16);
            uint2 st; st.x = lo; st.y = hi;
            *reinterpret_cast<uint2*>(
                &attb[((size_t)b * SEQ + qrow) * DMODEL + h * DK + df * 16 + g * 4]) = st;
        }
        __syncthreads();   // Ks/Vs reuse safety across halves
    }
}

// ---------------------------------------------------------------------------
// Kernel 3: output projection, bf16 MFMA, fp32 out.
// ---------------------------------------------------------------------------
__global__ __launch_bounds__(256) void out_mfma_kernel(
    const ushort_t* __restrict__ attb,  // [4096,1024] bf16
    const ushort_t* __restrict__ Wob,   // [1024,1024] bf16
    float* __restrict__ out)            // [4096,1024] fp32
{
    __shared__ ushort_t As[128][40];
    __shared__ ushort_t Bs[128][40];

    const int tid = threadIdx.x;
    const int w = tid >> 6, lane = tid & 63;
    const int lm = lane & 15, g = lane >> 4, lk8 = g * 8;
    const int wm = (w >> 1) * 64, wn = (w & 1) * 64;
    const int m0 = blockIdx.y * 128, n0 = blockIdx.x * 128;

    v4f acc[4][4] = {};

    for (int k0 = 0; k0 < DMODEL; k0 += 32) {
        short8 a[2], b[2];
#pragma unroll
        for (int rep = 0; rep < 2; ++rep) {
            const int c = tid + 256 * rep;
            const int r = c >> 2, q8 = (c & 3) * 8;
            a[rep] = *reinterpret_cast<const short8*>(&attb[(size_t)(m0 + r) * DMODEL + k0 + q8]);
            b[rep] = *reinterpret_cast<const short8*>(&Wob [(size_t)(n0 + r) * DMODEL + k0 + q8]);
        }
        __syncthreads();
#pragma unroll
        for (int rep = 0; rep < 2; ++rep) {
            const int c = tid + 256 * rep;
            const int r = c >> 2, q8 = (c & 3) * 8;
            *reinterpret_cast<short8*>(&As[r][q8]) = a[rep];
            *reinterpret_cast<short8*>(&Bs[r][q8]) = b[rep];
        }
        __syncthreads();

        short8 af[4], bfr[4];
#pragma unroll
        for (int mf = 0; mf < 4; ++mf) af[mf]  = *reinterpret_cast<const short8*>(&As[wm + mf * 16 + lm][lk8]);
#pragma unroll
        for (int nf = 0; nf < 4; ++nf) bfr[nf] = *reinterpret_cast<const short8*>(&Bs[wn + nf * 16 + lm][lk8]);
#pragma unroll
        for (int mf = 0; mf < 4; ++mf)
#pragma unroll
            for (int nf = 0; nf < 4; ++nf)
                acc[mf][nf] = __builtin_amdgcn_mfma_f32_16x16x32_bf16(af[mf], bfr[nf], acc[mf][nf], 0, 0, 0);
    }

#pragma unroll
    for (int mf = 0; mf < 4; ++mf)
#pragma unroll
        for (int reg = 0; reg < 4; ++reg) {
            const int m = m0 + wm + mf * 16 + g * 4 + reg;
#pragma unroll
            for (int nf = 0; nf < 4; ++nf) {
                const int n = n0 + wn + nf * 16 + lm;
                out[(size_t)m * DMODEL + n] = acc[mf][nf][reg];
            }
        }
}

// ---------------------------------------------------------------------------
extern "C" void kernel_launch(void* const* d_in, const int* in_sizes, int n_in,
                              void* d_out, int out_size, void* d_ws, size_t ws_size,
                              hipStream_t stream) {
    (void)in_sizes; (void)n_in; (void)out_size; (void)ws_size;

    const float* x    = (const float*)d_in[0];
    const float* Wa   = (const float*)d_in[1];
    const float* Wo   = (const float*)d_in[2];
    const float* rope = (const float*)d_in[3];
    const int*   tp   = (const int*)d_in[4];
    float* out = (float*)d_out;

    char* ws = (char*)d_ws;
    ushort_t* xb   = (ushort_t*)(ws);                       // 8 MB
    ushort_t* Wab  = (ushort_t*)(ws + (8u << 20));          // 6 MB
    ushort_t* Wob  = (ushort_t*)(ws + (14u << 20));         // 2 MB
    float*    cosT = (float*)   (ws + (16u << 20));         // 0.5 MB
    float*    sinT = (float*)   (ws + (16u << 20) + (512u << 10));
    ushort_t* Qb   = (ushort_t*)(ws + (17u << 20));         // 8 MB
    ushort_t* Kb   = (ushort_t*)(ws + (25u << 20));         // 8 MB
    ushort_t* Vb   = (ushort_t*)(ws + (33u << 20));         // 8 MB
    ushort_t* Vtb  = (ushort_t*)(ws + (41u << 20));         // 8 MB
    ushort_t* attb = (ushort_t*)(ws + (49u << 20));         // 8 MB

    dim3 blk(256);
    cvt_bf16_kernel<<<dim3((M_ROWS * DMODEL / 4) / 256), blk, 0, stream>>>(x,  xb,  M_ROWS * DMODEL / 4);
    cvt_bf16_kernel<<<dim3((NQKV  * DMODEL / 4) / 256), blk, 0, stream>>>(Wa, Wab, NQKV  * DMODEL / 4);
    cvt_bf16_kernel<<<dim3((DMODEL * DMODEL / 4) / 256), blk, 0, stream>>>(Wo, Wob, DMODEL * DMODEL / 4);
    rope_table_kernel<<<dim3(SEQ * DK / 256), blk, 0, stream>>>(rope, cosT, sinT);

    qkv_mfma_kernel<<<dim3(NQKV / 128, M_ROWS / 128), blk, 0, stream>>>(
        xb, Wab, cosT, sinT, tp, Qb, Kb, Vb);
    transpose_v_kernel<<<dim3(SEQ / 64, B_SZ * NH), blk, 0, stream>>>(Vb, Vtb);
    attn_mfma_kernel<<<dim3(16, NH, B_SZ), blk, 0, stream>>>(Qb, Kb, Vtb, attb);
    out_mfma_kernel<<<dim3(DMODEL / 128, M_ROWS / 128), blk, 0, stream>>>(attb, Wob, out);
}

// Round 6
// 254.837 us; speedup vs baseline: 1.7297x; 1.0513x over previous
//
#include <hip/hip_runtime.h>
#include <math.h>

// Problem constants
#define B_SZ 2
#define SEQ 2048
#define DMODEL 1024
#define NH 16
#define DK 64
#define NQKV 3072
#define M_ROWS 4096

#define NEG_BIG (-3.0e38f)

typedef short short8 __attribute__((ext_vector_type(8)));
typedef float v4f __attribute__((ext_vector_type(4)));
typedef unsigned short ushort_t;

__device__ inline ushort_t f2bf(float f) {
    unsigned u = __float_as_uint(f);
    u += 0x7fffu + ((u >> 16) & 1u);   // RNE
    return (ushort_t)(u >> 16);
}

// async global(16B/lane) -> LDS (wave-uniform base + lane*16)
__device__ __forceinline__ void gl_lds16(const ushort_t* g, ushort_t* l) {
    __builtin_amdgcn_global_load_lds(
        (const __attribute__((address_space(1))) unsigned int*)g,
        (__attribute__((address_space(3))) unsigned int*)l, 16, 0, 0);
}

// ---------------------------------------------------------------------------
// Kernel 0a: fp32 -> bf16 convert
// ---------------------------------------------------------------------------
__global__ __launch_bounds__(256) void cvt_bf16_kernel(
    const float* __restrict__ src, ushort_t* __restrict__ dst, int n4)
{
    int i = blockIdx.x * 256 + threadIdx.x;
    if (i < n4) {
        float4 v = reinterpret_cast<const float4*>(src)[i];
        ushort4 r;
        r.x = f2bf(v.x); r.y = f2bf(v.y); r.z = f2bf(v.z); r.w = f2bf(v.w);
        reinterpret_cast<ushort4*>(dst)[i] = r;
    }
}

// ---------------------------------------------------------------------------
// Kernel 0b: RoPE cos/sin tables from the [2048,64,64] matrix buffer.
// v'[d] = cosT[d]*v[d] + sinT[d]*v[d^1]  (sinT[even]=-s, sinT[odd]=+s)
// ---------------------------------------------------------------------------
__global__ __launch_bounds__(256) void rope_table_kernel(
    const float* __restrict__ rope, float* __restrict__ cosT, float* __restrict__ sinT)
{
    int i = blockIdx.x * 256 + threadIdx.x;   // [0, 2048*64)
    int p = i >> 6, d = i & 63;
    const float* Rp = rope + (size_t)p * 4096;
    float c = Rp[d * 64 + d];
    float s = Rp[(d | 1) * 64 + (d & ~1)];
    cosT[i] = c;
    sinT[i] = (d & 1) ? s : -s;
}

// ---------------------------------------------------------------------------
// Kernel 1: QKV projection + RoPE -> Q/K/V bf16 [B,H,S,DK]
// FLIPPED orientation: A = Wa (rows = e), B = xb (rows = m=s).
//   C/D: col=lm -> s, row=g*4+reg -> e  => per-lane regs = 4 consecutive d.
// m97-style K-loop: global_load_lds dwordx4 into unpadded [128][32] LDS.
// Epilogue: RoPE in-lane, stage 128x128 output tile in LDS (aliases As/Bs),
// then fully-coalesced 16B stores of the contiguous [s][d] head slabs.
// ---------------------------------------------------------------------------
#define ES_STRIDE 136
extern __shared__ ushort_t qkv_smem[];

__global__ __launch_bounds__(256) void qkv_mfma_kernel(
    const ushort_t* __restrict__ xb,   // [4096,1024] bf16
    const ushort_t* __restrict__ Wab,  // [3072,1024] bf16
    const float* __restrict__ cosT, const float* __restrict__ sinT,
    const int* __restrict__ tpos,
    ushort_t* __restrict__ Qb, ushort_t* __restrict__ Kb, ushort_t* __restrict__ Vb)
{
    ushort_t* As = qkv_smem;           // [128][32] unpadded (A = Wa tile)
    ushort_t* Bs = qkv_smem + 4096;    // [128][32] unpadded (B = xb tile)
    ushort_t* Es = qkv_smem;           // [128][ES_STRIDE] epilogue tile (aliases)

    const int tid = threadIdx.x;
    const int w = tid >> 6, lane = tid & 63;
    const int lm = lane & 15, g = lane >> 4, lk8 = g * 8;
    const int wm = (w >> 1) * 64, wn = (w & 1) * 64;   // wm: e-dim, wn: m-dim
    const int e0 = blockIdx.x * 128, m0 = blockIdx.y * 128;

    const int lrow = lane >> 2;          // 0..15
    const int lcol8 = (lane & 3) * 8;    // ushort col offset

    v4f acc[4][4] = {};

    for (int k0 = 0; k0 < DMODEL; k0 += 32) {
        __syncthreads();   // previous iter's frag reads done
#pragma unroll
        for (int j = 0; j < 2; ++j) {
            const int rA = w * 32 + j * 16;
            gl_lds16(&Wab[(size_t)(e0 + rA + lrow) * DMODEL + k0 + lcol8], &As[rA * 32]);
            gl_lds16(&xb [(size_t)(m0 + rA + lrow) * DMODEL + k0 + lcol8], &Bs[rA * 32]);
        }
        __syncthreads();   // drains vmcnt -> LDS visible

        short8 af[4], bfr[4];
#pragma unroll
        for (int mf = 0; mf < 4; ++mf) af[mf]  = *reinterpret_cast<const short8*>(&As[(wm + mf * 16 + lm) * 32 + lk8]);
#pragma unroll
        for (int nf = 0; nf < 4; ++nf) bfr[nf] = *reinterpret_cast<const short8*>(&Bs[(wn + nf * 16 + lm) * 32 + lk8]);
#pragma unroll
        for (int mf = 0; mf < 4; ++mf)
#pragma unroll
            for (int nf = 0; nf < 4; ++nf)
                acc[mf][nf] = __builtin_amdgcn_mfma_f32_16x16x32_bf16(af[mf], bfr[nf], acc[mf][nf], 0, 0, 0);
    }

    __syncthreads();   // all frag reads done; Es may alias As/Bs

    const int which = e0 >> 10;            // 0=Q,1=K,2=V (block-uniform)
    ushort_t* buf = (which == 0) ? Qb : ((which == 1) ? Kb : Vb);
    const int h0 = (e0 & 1023) >> 6;       // first of the 2 heads this tile spans
    const int bb = m0 >> 11, s0 = m0 & 2047;

    // RoPE (in-lane) + write Es[s_loc][e_loc]
#pragma unroll
    for (int mf = 0; mf < 4; ++mf) {
        const int ebase = wm + mf * 16 + g * 4;     // local e of reg 0 (mult of 4)
        const int d0 = (e0 + ebase) & 63;
#pragma unroll
        for (int nf = 0; nf < 4; ++nf) {
            const int sloc = wn + nf * 16 + lm;
            float v[4] = {acc[mf][nf][0], acc[mf][nf][1], acc[mf][nf][2], acc[mf][nf][3]};
            if (which < 2) {
                const int p = tpos[s0 + sloc];
                const float4 c4 = *reinterpret_cast<const float4*>(&cosT[p * 64 + d0]);
                const float4 s4 = *reinterpret_cast<const float4*>(&sinT[p * 64 + d0]);
                const float r0 = c4.x * v[0] + s4.x * v[1];
                const float r1 = c4.y * v[1] + s4.y * v[0];
                const float r2 = c4.z * v[2] + s4.z * v[3];
                const float r3 = c4.w * v[3] + s4.w * v[2];
                v[0] = r0; v[1] = r1; v[2] = r2; v[3] = r3;
            }
            uint2 pp;
            pp.x = (unsigned)f2bf(v[0]) | ((unsigned)f2bf(v[1]) << 16);
            pp.y = (unsigned)f2bf(v[2]) | ((unsigned)f2bf(v[3]) << 16);
            *reinterpret_cast<uint2*>(&Es[sloc * ES_STRIDE + ebase]) = pp;
        }
    }
    __syncthreads();

    // coalesced store: per head-half hh, region buf[((bb*NH+h0+hh)*SEQ+s0)*64 ..]
    // is 8192 contiguous ushorts ([s][d], d==64). 4 insts x 256 thr x 8 ushort.
#pragma unroll
    for (int hh = 0; hh < 2; ++hh) {
        ushort_t* dst = buf + (((size_t)bb * NH + h0 + hh) * SEQ + s0) * DK;
#pragma unroll
        for (int t = 0; t < 4; ++t) {
            const int o = (t * 256 + tid) * 8;
            const int sloc = o >> 6, d = o & 63;
            const short8 vv = *reinterpret_cast<const short8*>(&Es[sloc * ES_STRIDE + hh * 64 + d]);
            *reinterpret_cast<short8*>(&dst[o]) = vv;
        }
    }
}

// ---------------------------------------------------------------------------
// Kernel 1b: transpose V [B,H,S,DK] -> Vt [B,H,DK,S] (bf16)
// ---------------------------------------------------------------------------
__global__ __launch_bounds__(256) void transpose_v_kernel(
    const ushort_t* __restrict__ Vb, ushort_t* __restrict__ Vtb)
{
    __shared__ ushort_t t[64][72];
    const int tid = threadIdx.x;
    const int s0 = blockIdx.x * 64;
    const int hb = blockIdx.y;                 // b*NH+h
    const size_t base = (size_t)hb * SEQ * DK;
#pragma unroll
    for (int r = 0; r < 2; ++r) {
        const int c = tid + 256 * r;
        const int row = c >> 3, col8 = (c & 7) * 8;
        short8 v = *reinterpret_cast<const short8*>(&Vb[base + (size_t)(s0 + row) * DK + col8]);
#pragma unroll
        for (int j = 0; j < 8; ++j) t[col8 + j][row] = (ushort_t)v[j];
    }
    __syncthreads();
#pragma unroll
    for (int r = 0; r < 2; ++r) {
        const int c = tid + 256 * r;
        const int drow = c >> 3, s8 = (c & 7) * 8;
        short8 v = *reinterpret_cast<const short8*>(&t[drow][s8]);
        *reinterpret_cast<short8*>(&Vtb[base + (size_t)drow * SEQ + s0 + s8]) = v;
    }
}

// ---------------------------------------------------------------------------
// Kernel 2: flash attention (unchanged from R5 — verified fast & correct).
// ---------------------------------------------------------------------------
__global__ __launch_bounds__(256) void attn_mfma_kernel(
    const ushort_t* __restrict__ Qb, const ushort_t* __restrict__ Kb,
    const ushort_t* __restrict__ Vtb, ushort_t* __restrict__ attb)
{
    __shared__ ushort_t Ks[64][72];    // [kv][d]
    __shared__ ushort_t Vs[64][72];    // [d][kv]  (V^T)
    __shared__ ushort_t Ps[64][72];    // [q][kv]; wave w owns rows [16w,16w+16)

    const int tid = threadIdx.x;
    const int w = tid >> 6, lane = tid & 63;
    const int lm = lane & 15, g = lane >> 4, lk8 = g * 8;

    const int u = blockIdx.x;                     // 0..15
    const int h = blockIdx.y, b = blockIdx.z;
    const size_t ho = ((size_t)b * NH + h) * SEQ * DK;
    const ushort_t* Qh = Qb + ho;
    const ushort_t* Kh = Kb + ho;
    const ushort_t* Vth = Vtb + ho;               // [DK][SEQ]

#pragma unroll
    for (int half = 0; half < 2; ++half) {
        const int it = half ? (31 - u) : u;
        const int q0 = it * 64;
        const int qrow = q0 + w * 16 + lm;

        short8 qf0 = *reinterpret_cast<const short8*>(&Qh[(size_t)qrow * DK + lk8]);
        short8 qf1 = *reinterpret_cast<const short8*>(&Qh[(size_t)qrow * DK + 32 + lk8]);

        float m_i = NEG_BIG, l_i = 0.f;
        v4f Oa[4] = {};   // O^T: row d = df*16+g*4+reg, col q = lm

        for (int jt = 0; jt <= it; ++jt) {
            const int c0 = jt * 64;

            short8 kreg[2], vreg[2];
            int rr[2], cc8[2];
#pragma unroll
            for (int rep = 0; rep < 2; ++rep) {
                const int c = tid + 256 * rep;
                rr[rep] = c >> 3; cc8[rep] = (c & 7) * 8;
                kreg[rep] = *reinterpret_cast<const short8*>(&Kh[(size_t)(c0 + rr[rep]) * DK + cc8[rep]]);
                vreg[rep] = *reinterpret_cast<const short8*>(&Vth[(size_t)rr[rep] * SEQ + c0 + cc8[rep]]);
            }
            __syncthreads();
#pragma unroll
            for (int rep = 0; rep < 2; ++rep) {
                *reinterpret_cast<short8*>(&Ks[rr[rep]][cc8[rep]]) = kreg[rep];
                *reinterpret_cast<short8*>(&Vs[rr[rep]][cc8[rep]]) = vreg[rep];
            }
            __syncthreads();

            // S^T = K Q^T
            v4f sacc[4] = {};
#pragma unroll
            for (int nf = 0; nf < 4; ++nf) {
                const short8 kf0 = *reinterpret_cast<const short8*>(&Ks[nf * 16 + lm][lk8]);
                const short8 kf1 = *reinterpret_cast<const short8*>(&Ks[nf * 16 + lm][32 + lk8]);
                sacc[nf] = __builtin_amdgcn_mfma_f32_16x16x32_bf16(kf0, qf0, sacc[nf], 0, 0, 0);
                sacc[nf] = __builtin_amdgcn_mfma_f32_16x16x32_bf16(kf1, qf1, sacc[nf], 0, 0, 0);
            }

            if (jt == it) {
#pragma unroll
                for (int nf = 0; nf < 4; ++nf)
#pragma unroll
                    for (int reg = 0; reg < 4; ++reg) {
                        const int kv = c0 + nf * 16 + g * 4 + reg;
                        const float sv = sacc[nf][reg] * 0.125f;
                        sacc[nf][reg] = (kv > qrow) ? NEG_BIG : sv;
                    }
            } else {
#pragma unroll
                for (int nf = 0; nf < 4; ++nf)
#pragma unroll
                    for (int reg = 0; reg < 4; ++reg) sacc[nf][reg] *= 0.125f;
            }

            float mloc = sacc[0][0];
#pragma unroll
            for (int nf = 0; nf < 4; ++nf)
#pragma unroll
                for (int reg = 0; reg < 4; ++reg) mloc = fmaxf(mloc, sacc[nf][reg]);
            mloc = fmaxf(mloc, __shfl_xor(mloc, 16, 64));
            mloc = fmaxf(mloc, __shfl_xor(mloc, 32, 64));
            const float mnew = fmaxf(m_i, mloc);
            const float alpha = __expf(m_i - mnew);
            float rs = 0.f;
#pragma unroll
            for (int nf = 0; nf < 4; ++nf)
#pragma unroll
                for (int reg = 0; reg < 4; ++reg) {
                    const float p = __expf(sacc[nf][reg] - mnew);
                    sacc[nf][reg] = p;
                    rs += p;
                }
            rs += __shfl_xor(rs, 16, 64);
            rs += __shfl_xor(rs, 32, 64);
            l_i = l_i * alpha + rs;
            m_i = mnew;
#pragma unroll
            for (int df = 0; df < 4; ++df)
#pragma unroll
                for (int reg = 0; reg < 4; ++reg) Oa[df][reg] *= alpha;

#pragma unroll
            for (int nf = 0; nf < 4; ++nf) {
                uint2 pp;
                pp.x = (unsigned)f2bf(sacc[nf][0]) | ((unsigned)f2bf(sacc[nf][1]) << 16);
                pp.y = (unsigned)f2bf(sacc[nf][2]) | ((unsigned)f2bf(sacc[nf][3]) << 16);
                *reinterpret_cast<uint2*>(&Ps[w * 16 + lm][nf * 16 + g * 4]) = pp;
            }

#pragma unroll
            for (int kc = 0; kc < 2; ++kc) {
                const short8 pf = *reinterpret_cast<const short8*>(&Ps[w * 16 + lm][kc * 32 + lk8]);
#pragma unroll
                for (int df = 0; df < 4; ++df) {
                    const short8 vf = *reinterpret_cast<const short8*>(&Vs[df * 16 + lm][kc * 32 + lk8]);
                    Oa[df] = __builtin_amdgcn_mfma_f32_16x16x32_bf16(vf, pf, Oa[df], 0, 0, 0);
                }
            }
        }

        const float inv = 1.0f / l_i;
#pragma unroll
        for (int df = 0; df < 4; ++df) {
            const unsigned lo = (unsigned)f2bf(Oa[df][0] * inv) | ((unsigned)f2bf(Oa[df][1] * inv) << 16);
            const unsigned hi = (unsigned)f2bf(Oa[df][2] * inv) | ((unsigned)f2bf(Oa[df][3] * inv) << 16);
            uint2 st; st.x = lo; st.y = hi;
            *reinterpret_cast<uint2*>(
                &attb[((size_t)b * SEQ + qrow) * DMODEL + h * DK + df * 16 + g * 4]) = st;
        }
        __syncthreads();
    }
}

// ---------------------------------------------------------------------------
// Kernel 3: output projection, m97-style global_load_lds staging.
// ---------------------------------------------------------------------------
__global__ __launch_bounds__(256) void out_mfma_kernel(
    const ushort_t* __restrict__ attb,  // [4096,1024] bf16
    const ushort_t* __restrict__ Wob,   // [1024,1024] bf16
    float* __restrict__ out)            // [4096,1024] fp32
{
    __shared__ ushort_t As[128 * 32];   // [m][k] unpadded
    __shared__ ushort_t Bs[128 * 32];   // [n][k]

    const int tid = threadIdx.x;
    const int w = tid >> 6, lane = tid & 63;
    const int lm = lane & 15, g = lane >> 4, lk8 = g * 8;
    const int wm = (w >> 1) * 64, wn = (w & 1) * 64;
    const int m0 = blockIdx.y * 128, n0 = blockIdx.x * 128;

    const int lrow = lane >> 2;
    const int lcol8 = (lane & 3) * 8;

    v4f acc[4][4] = {};

    for (int k0 = 0; k0 < DMODEL; k0 += 32) {
        __syncthreads();
#pragma unroll
        for (int j = 0; j < 2; ++j) {
            const int rA = w * 32 + j * 16;
            gl_lds16(&attb[(size_t)(m0 + rA + lrow) * DMODEL + k0 + lcol8], &As[rA * 32]);
            gl_lds16(&Wob [(size_t)(n0 + rA + lrow) * DMODEL + k0 + lcol8], &Bs[rA * 32]);
        }
        __syncthreads();

        short8 af[4], bfr[4];
#pragma unroll
        for (int mf = 0; mf < 4; ++mf) af[mf]  = *reinterpret_cast<const short8*>(&As[(wm + mf * 16 + lm) * 32 + lk8]);
#pragma unroll
        for (int nf = 0; nf < 4; ++nf) bfr[nf] = *reinterpret_cast<const short8*>(&Bs[(wn + nf * 16 + lm) * 32 + lk8]);
#pragma unroll
        for (int mf = 0; mf < 4; ++mf)
#pragma unroll
            for (int nf = 0; nf < 4; ++nf)
                acc[mf][nf] = __builtin_amdgcn_mfma_f32_16x16x32_bf16(af[mf], bfr[nf], acc[mf][nf], 0, 0, 0);
    }

#pragma unroll
    for (int mf = 0; mf < 4; ++mf)
#pragma unroll
        for (int reg = 0; reg < 4; ++reg) {
            const int m = m0 + wm + mf * 16 + g * 4 + reg;
#pragma unroll
            for (int nf = 0; nf < 4; ++nf) {
                const int n = n0 + wn + nf * 16 + lm;
                out[(size_t)m * DMODEL + n] = acc[mf][nf][reg];
            }
        }
}

// ---------------------------------------------------------------------------
extern "C" void kernel_launch(void* const* d_in, const int* in_sizes, int n_in,
                              void* d_out, int out_size, void* d_ws, size_t ws_size,
                              hipStream_t stream) {
    (void)in_sizes; (void)n_in; (void)out_size; (void)ws_size;

    const float* x    = (const float*)d_in[0];
    const float* Wa   = (const float*)d_in[1];
    const float* Wo   = (const float*)d_in[2];
    const float* rope = (const float*)d_in[3];
    const int*   tp   = (const int*)d_in[4];
    float* out = (float*)d_out;

    char* ws = (char*)d_ws;
    ushort_t* xb   = (ushort_t*)(ws);                       // 8 MB
    ushort_t* Wab  = (ushort_t*)(ws + (8u << 20));          // 6 MB
    ushort_t* Wob  = (ushort_t*)(ws + (14u << 20));         // 2 MB
    float*    cosT = (float*)   (ws + (16u << 20));         // 0.5 MB
    float*    sinT = (float*)   (ws + (16u << 20) + (512u << 10));
    ushort_t* Qb   = (ushort_t*)(ws + (17u << 20));         // 8 MB
    ushort_t* Kb   = (ushort_t*)(ws + (25u << 20));         // 8 MB
    ushort_t* Vb   = (ushort_t*)(ws + (33u << 20));         // 8 MB
    ushort_t* Vtb  = (ushort_t*)(ws + (41u << 20));         // 8 MB
    ushort_t* attb = (ushort_t*)(ws + (49u << 20));         // 8 MB

    dim3 blk(256);
    cvt_bf16_kernel<<<dim3((M_ROWS * DMODEL / 4) / 256), blk, 0, stream>>>(x,  xb,  M_ROWS * DMODEL / 4);
    cvt_bf16_kernel<<<dim3((NQKV  * DMODEL / 4) / 256), blk, 0, stream>>>(Wa, Wab, NQKV  * DMODEL / 4);
    cvt_bf16_kernel<<<dim3((DMODEL * DMODEL / 4) / 256), blk, 0, stream>>>(Wo, Wob, DMODEL * DMODEL / 4);
    rope_table_kernel<<<dim3(SEQ * DK / 256), blk, 0, stream>>>(rope, cosT, sinT);

    const size_t qkv_lds = 128 * ES_STRIDE * sizeof(ushort_t);  // 34816 B (> 2*8KB staging)
    qkv_mfma_kernel<<<dim3(NQKV / 128, M_ROWS / 128), blk, qkv_lds, stream>>>(
        xb, Wab, cosT, sinT, tp, Qb, Kb, Vb);
    transpose_v_kernel<<<dim3(SEQ / 64, B_SZ * NH), blk, 0, stream>>>(Vb, Vtb);
    attn_mfma_kernel<<<dim3(16, NH, B_SZ), blk, 0, stream>>>(Qb, Kb, Vtb, attb);
    out_mfma_kernel<<<dim3(DMODEL / 128, M_ROWS / 128), blk, 0, stream>>>(attb, Wob, out);
}

// Round 8
// 251.634 us; speedup vs baseline: 1.7518x; 1.0127x over previous
//
#include <hip/hip_runtime.h>
#include <math.h>

// Problem constants
#define B_SZ 2
#define SEQ 2048
#define DMODEL 1024
#define NH 16
#define DK 64
#define NQKV 3072
#define M_ROWS 4096

#define NEG_BIG (-3.0e38f)

typedef short short8 __attribute__((ext_vector_type(8)));
typedef float v4f __attribute__((ext_vector_type(4)));
typedef unsigned short ushort_t;

__device__ inline ushort_t f2bf(float f) {
    unsigned u = __float_as_uint(f);
    u += 0x7fffu + ((u >> 16) & 1u);   // RNE
    return (ushort_t)(u >> 16);
}

// async global(16B/lane) -> LDS (wave-uniform base + lane*16)
__device__ __forceinline__ void gl_lds16(const ushort_t* g, ushort_t* l) {
    __builtin_amdgcn_global_load_lds(
        (const __attribute__((address_space(1))) unsigned int*)g,
        (__attribute__((address_space(3))) unsigned int*)l, 16, 0, 0);
}

// ---------------------------------------------------------------------------
// Kernel 0: fused prep — fp32->bf16 converts (x, Wa, Wo) + RoPE tables.
// Block ranges: [0,4096) x | [4096,7168) Wa | [7168,8192) Wo | [8192,8704) rope
// ---------------------------------------------------------------------------
__global__ __launch_bounds__(256) void prep_kernel(
    const float* __restrict__ x, const float* __restrict__ Wa,
    const float* __restrict__ Wo, const float* __restrict__ rope,
    ushort_t* __restrict__ xb, ushort_t* __restrict__ Wab, ushort_t* __restrict__ Wob,
    float* __restrict__ cosT, float* __restrict__ sinT)
{
    const int bid = blockIdx.x;
    if (bid < 8192) {
        const float* src; ushort_t* dst; int i;
        if (bid < 4096)      { src = x;  dst = xb;  i = bid * 256 + threadIdx.x; }
        else if (bid < 7168) { src = Wa; dst = Wab; i = (bid - 4096) * 256 + threadIdx.x; }
        else                 { src = Wo; dst = Wob; i = (bid - 7168) * 256 + threadIdx.x; }
        float4 v = reinterpret_cast<const float4*>(src)[i];
        ushort4 r;
        r.x = f2bf(v.x); r.y = f2bf(v.y); r.z = f2bf(v.z); r.w = f2bf(v.w);
        reinterpret_cast<ushort4*>(dst)[i] = r;
    } else {
        const int i = (bid - 8192) * 256 + threadIdx.x;   // [0, 2048*64)
        const int p = i >> 6, d = i & 63;
        const float* Rp = rope + (size_t)p * 4096;
        const float c = Rp[d * 64 + d];
        const float s = Rp[(d | 1) * 64 + (d & ~1)];
        cosT[i] = c;
        sinT[i] = (d & 1) ? s : -s;
    }
}

// ---------------------------------------------------------------------------
// Kernel 1: QKV projection + RoPE -> Q/K/V bf16 [B,H,S,DK]
// R6-verified structure: 2-barrier K-loop, single-buffer gl_lds staging.
// A = Wa (rows e), B = xb (rows s). C/D: col=lm -> s, row=g*4+reg -> e.
// ---------------------------------------------------------------------------
#define ES_STRIDE 136
extern __shared__ ushort_t qkv_smem[];

__global__ __launch_bounds__(256) void qkv_mfma_kernel(
    const ushort_t* __restrict__ xb,   // [4096,1024] bf16
    const ushort_t* __restrict__ Wab,  // [3072,1024] bf16
    const float* __restrict__ cosT, const float* __restrict__ sinT,
    const int* __restrict__ tpos,
    ushort_t* __restrict__ Qb, ushort_t* __restrict__ Kb, ushort_t* __restrict__ Vb)
{
    ushort_t* As = qkv_smem;           // [128][32] unpadded (A = Wa tile)
    ushort_t* Bs = qkv_smem + 4096;    // [128][32] unpadded (B = xb tile)
    ushort_t* Es = qkv_smem;           // [128][ES_STRIDE] epilogue tile (aliases)

    const int tid = threadIdx.x;
    const int w = tid >> 6, lane = tid & 63;
    const int lm = lane & 15, g = lane >> 4, lk8 = g * 8;
    const int wm = (w >> 1) * 64, wn = (w & 1) * 64;   // wm: e-dim, wn: m-dim
    const int e0 = blockIdx.x * 128, m0 = blockIdx.y * 128;

    const int lrow = lane >> 2;          // 0..15
    const int lcol8 = (lane & 3) * 8;    // ushort col offset

    v4f acc[4][4] = {};

    for (int k0 = 0; k0 < DMODEL; k0 += 32) {
        __syncthreads();   // previous iter's frag reads done
#pragma unroll
        for (int j = 0; j < 2; ++j) {
            const int rA = w * 32 + j * 16;
            gl_lds16(&Wab[(size_t)(e0 + rA + lrow) * DMODEL + k0 + lcol8], &As[rA * 32]);
            gl_lds16(&xb [(size_t)(m0 + rA + lrow) * DMODEL + k0 + lcol8], &Bs[rA * 32]);
        }
        __syncthreads();   // drains vmcnt -> LDS visible

        short8 af[4], bfr[4];
#pragma unroll
        for (int mf = 0; mf < 4; ++mf) af[mf]  = *reinterpret_cast<const short8*>(&As[(wm + mf * 16 + lm) * 32 + lk8]);
#pragma unroll
        for (int nf = 0; nf < 4; ++nf) bfr[nf] = *reinterpret_cast<const short8*>(&Bs[(wn + nf * 16 + lm) * 32 + lk8]);
#pragma unroll
        for (int mf = 0; mf < 4; ++mf)
#pragma unroll
            for (int nf = 0; nf < 4; ++nf)
                acc[mf][nf] = __builtin_amdgcn_mfma_f32_16x16x32_bf16(af[mf], bfr[nf], acc[mf][nf], 0, 0, 0);
    }

    __syncthreads();   // all frag reads done; Es may alias As/Bs

    const int which = e0 >> 10;            // 0=Q,1=K,2=V (block-uniform)
    ushort_t* buf = (which == 0) ? Qb : ((which == 1) ? Kb : Vb);
    const int h0 = (e0 & 1023) >> 6;
    const int bb = m0 >> 11, s0 = m0 & 2047;

    // RoPE (in-lane) + write Es[s_loc][e_loc]
#pragma unroll
    for (int mf = 0; mf < 4; ++mf) {
        const int ebase = wm + mf * 16 + g * 4;
        const int d0 = (e0 + ebase) & 63;
#pragma unroll
        for (int nf = 0; nf < 4; ++nf) {
            const int sloc = wn + nf * 16 + lm;
            float v[4] = {acc[mf][nf][0], acc[mf][nf][1], acc[mf][nf][2], acc[mf][nf][3]};
            if (which < 2) {
                const int p = tpos[s0 + sloc];
                const float4 c4 = *reinterpret_cast<const float4*>(&cosT[p * 64 + d0]);
                const float4 s4 = *reinterpret_cast<const float4*>(&sinT[p * 64 + d0]);
                const float r0 = c4.x * v[0] + s4.x * v[1];
                const float r1 = c4.y * v[1] + s4.y * v[0];
                const float r2 = c4.z * v[2] + s4.z * v[3];
                const float r3 = c4.w * v[3] + s4.w * v[2];
                v[0] = r0; v[1] = r1; v[2] = r2; v[3] = r3;
            }
            uint2 pp;
            pp.x = (unsigned)f2bf(v[0]) | ((unsigned)f2bf(v[1]) << 16);
            pp.y = (unsigned)f2bf(v[2]) | ((unsigned)f2bf(v[3]) << 16);
            *reinterpret_cast<uint2*>(&Es[sloc * ES_STRIDE + ebase]) = pp;
        }
    }
    __syncthreads();

    // coalesced store of contiguous [s][d] head slabs
#pragma unroll
    for (int hh = 0; hh < 2; ++hh) {
        ushort_t* dst = buf + (((size_t)bb * NH + h0 + hh) * SEQ + s0) * DK;
#pragma unroll
        for (int t = 0; t < 4; ++t) {
            const int o = (t * 256 + tid) * 8;
            const int sloc = o >> 6, d = o & 63;
            const short8 vv = *reinterpret_cast<const short8*>(&Es[sloc * ES_STRIDE + hh * 64 + d]);
            *reinterpret_cast<short8*>(&dst[o]) = vv;
        }
    }
}

// ---------------------------------------------------------------------------
// Kernel 1b: transpose V [B,H,S,DK] -> Vt [B,H,DK,S] (bf16)
// ---------------------------------------------------------------------------
__global__ __launch_bounds__(256) void transpose_v_kernel(
    const ushort_t* __restrict__ Vb, ushort_t* __restrict__ Vtb)
{
    __shared__ ushort_t t[64][72];
    const int tid = threadIdx.x;
    const int s0 = blockIdx.x * 64;
    const int hb = blockIdx.y;                 // b*NH+h
    const size_t base = (size_t)hb * SEQ * DK;
#pragma unroll
    for (int r = 0; r < 2; ++r) {
        const int c = tid + 256 * r;
        const int row = c >> 3, col8 = (c & 7) * 8;
        short8 v = *reinterpret_cast<const short8*>(&Vb[base + (size_t)(s0 + row) * DK + col8]);
#pragma unroll
        for (int j = 0; j < 8; ++j) t[col8 + j][row] = (ushort_t)v[j];
    }
    __syncthreads();
#pragma unroll
    for (int r = 0; r < 2; ++r) {
        const int c = tid + 256 * r;
        const int drow = c >> 3, s8 = (c & 7) * 8;
        short8 v = *reinterpret_cast<const short8*>(&t[drow][s8]);
        *reinterpret_cast<short8*>(&Vtb[base + (size_t)drow * SEQ + s0 + s8]) = v;
    }
}

// ---------------------------------------------------------------------------
// Kernel 2: flash attention, software-pipelined K/V register prefetch.
// R5/R6-verified barrier pattern (incl. trailing half barrier) + prefetch.
// ---------------------------------------------------------------------------
__global__ __launch_bounds__(256) void attn_mfma_kernel(
    const ushort_t* __restrict__ Qb, const ushort_t* __restrict__ Kb,
    const ushort_t* __restrict__ Vtb, ushort_t* __restrict__ attb)
{
    __shared__ ushort_t Ks[64][72];    // [kv][d]
    __shared__ ushort_t Vs[64][72];    // [d][kv]  (V^T)
    __shared__ ushort_t Ps[64][72];    // [q][kv]; wave w owns rows [16w,16w+16)

    const int tid = threadIdx.x;
    const int w = tid >> 6, lane = tid & 63;
    const int lm = lane & 15, g = lane >> 4, lk8 = g * 8;

    const int u = blockIdx.x;                     // 0..15
    const int h = blockIdx.y, b = blockIdx.z;
    const size_t ho = ((size_t)b * NH + h) * SEQ * DK;
    const ushort_t* Qh = Qb + ho;
    const ushort_t* Kh = Kb + ho;
    const ushort_t* Vth = Vtb + ho;               // [DK][SEQ]

    const int rr0 = tid >> 3, cc80 = (tid & 7) * 8;
    const int rr1 = (tid + 256) >> 3, cc81 = ((tid + 256) & 7) * 8;

#pragma unroll
    for (int half = 0; half < 2; ++half) {
        const int it = half ? (31 - u) : u;
        const int q0 = it * 64;
        const int qrow = q0 + w * 16 + lm;

        short8 qf0 = *reinterpret_cast<const short8*>(&Qh[(size_t)qrow * DK + lk8]);
        short8 qf1 = *reinterpret_cast<const short8*>(&Qh[(size_t)qrow * DK + 32 + lk8]);

        float m_i = NEG_BIG, l_i = 0.f;
        v4f Oa[4] = {};   // O^T: row d = df*16+g*4+reg, col q = lm

        // preload jt=0
        short8 kreg[2], vreg[2];
        kreg[0] = *reinterpret_cast<const short8*>(&Kh[(size_t)rr0 * DK + cc80]);
        kreg[1] = *reinterpret_cast<const short8*>(&Kh[(size_t)rr1 * DK + cc81]);
        vreg[0] = *reinterpret_cast<const short8*>(&Vth[(size_t)rr0 * SEQ + cc80]);
        vreg[1] = *reinterpret_cast<const short8*>(&Vth[(size_t)rr1 * SEQ + cc81]);

        for (int jt = 0; jt <= it; ++jt) {
            const int c0 = jt * 64;

            __syncthreads();   // prior iter's frag reads of Ks/Vs done
            *reinterpret_cast<short8*>(&Ks[rr0][cc80]) = kreg[0];
            *reinterpret_cast<short8*>(&Ks[rr1][cc81]) = kreg[1];
            *reinterpret_cast<short8*>(&Vs[rr0][cc80]) = vreg[0];
            *reinterpret_cast<short8*>(&Vs[rr1][cc81]) = vreg[1];
            __syncthreads();   // staged

            if (jt < it) {     // prefetch next tile; latency hides behind compute
                const int c0n = c0 + 64;
                kreg[0] = *reinterpret_cast<const short8*>(&Kh[(size_t)(c0n + rr0) * DK + cc80]);
                kreg[1] = *reinterpret_cast<const short8*>(&Kh[(size_t)(c0n + rr1) * DK + cc81]);
                vreg[0] = *reinterpret_cast<const short8*>(&Vth[(size_t)rr0 * SEQ + c0n + cc80]);
                vreg[1] = *reinterpret_cast<const short8*>(&Vth[(size_t)rr1 * SEQ + c0n + cc81]);
            }

            // S^T = K Q^T
            v4f sacc[4] = {};
#pragma unroll
            for (int nf = 0; nf < 4; ++nf) {
                const short8 kf0 = *reinterpret_cast<const short8*>(&Ks[nf * 16 + lm][lk8]);
                const short8 kf1 = *reinterpret_cast<const short8*>(&Ks[nf * 16 + lm][32 + lk8]);
                sacc[nf] = __builtin_amdgcn_mfma_f32_16x16x32_bf16(kf0, qf0, sacc[nf], 0, 0, 0);
                sacc[nf] = __builtin_amdgcn_mfma_f32_16x16x32_bf16(kf1, qf1, sacc[nf], 0, 0, 0);
            }

            if (jt == it) {
#pragma unroll
                for (int nf = 0; nf < 4; ++nf)
#pragma unroll
                    for (int reg = 0; reg < 4; ++reg) {
                        const int kv = c0 + nf * 16 + g * 4 + reg;
                        const float sv = sacc[nf][reg] * 0.125f;
                        sacc[nf][reg] = (kv > qrow) ? NEG_BIG : sv;
                    }
            } else {
#pragma unroll
                for (int nf = 0; nf < 4; ++nf)
#pragma unroll
                    for (int reg = 0; reg < 4; ++reg) sacc[nf][reg] *= 0.125f;
            }

            float mloc = sacc[0][0];
#pragma unroll
            for (int nf = 0; nf < 4; ++nf)
#pragma unroll
                for (int reg = 0; reg < 4; ++reg) mloc = fmaxf(mloc, sacc[nf][reg]);
            mloc = fmaxf(mloc, __shfl_xor(mloc, 16, 64));
            mloc = fmaxf(mloc, __shfl_xor(mloc, 32, 64));
            const float mnew = fmaxf(m_i, mloc);
            const float alpha = __expf(m_i - mnew);
            float rs = 0.f;
#pragma unroll
            for (int nf = 0; nf < 4; ++nf)
#pragma unroll
                for (int reg = 0; reg < 4; ++reg) {
                    const float p = __expf(sacc[nf][reg] - mnew);
                    sacc[nf][reg] = p;
                    rs += p;
                }
            rs += __shfl_xor(rs, 16, 64);
            rs += __shfl_xor(rs, 32, 64);
            l_i = l_i * alpha + rs;
            m_i = mnew;
#pragma unroll
            for (int df = 0; df < 4; ++df)
#pragma unroll
                for (int reg = 0; reg < 4; ++reg) Oa[df][reg] *= alpha;

            // wave-private P rows: no barrier needed
#pragma unroll
            for (int nf = 0; nf < 4; ++nf) {
                uint2 pp;
                pp.x = (unsigned)f2bf(sacc[nf][0]) | ((unsigned)f2bf(sacc[nf][1]) << 16);
                pp.y = (unsigned)f2bf(sacc[nf][2]) | ((unsigned)f2bf(sacc[nf][3]) << 16);
                *reinterpret_cast<uint2*>(&Ps[w * 16 + lm][nf * 16 + g * 4]) = pp;
            }

#pragma unroll
            for (int kc = 0; kc < 2; ++kc) {
                const short8 pf = *reinterpret_cast<const short8*>(&Ps[w * 16 + lm][kc * 32 + lk8]);
#pragma unroll
                for (int df = 0; df < 4; ++df) {
                    const short8 vf = *reinterpret_cast<const short8*>(&Vs[df * 16 + lm][kc * 32 + lk8]);
                    Oa[df] = __builtin_amdgcn_mfma_f32_16x16x32_bf16(vf, pf, Oa[df], 0, 0, 0);
                }
            }
        }

        const float inv = 1.0f / l_i;
#pragma unroll
        for (int df = 0; df < 4; ++df) {
            const unsigned lo = (unsigned)f2bf(Oa[df][0] * inv) | ((unsigned)f2bf(Oa[df][1] * inv) << 16);
            const unsigned hi = (unsigned)f2bf(Oa[df][2] * inv) | ((unsigned)f2bf(Oa[df][3] * inv) << 16);
            uint2 st; st.x = lo; st.y = hi;
            *reinterpret_cast<uint2*>(
                &attb[((size_t)b * SEQ + qrow) * DMODEL + h * DK + df * 16 + g * 4]) = st;
        }
        __syncthreads();   // Ks/Vs reuse safety across halves (verified R5/R6 pattern)
    }
}

// ---------------------------------------------------------------------------
// Kernel 3: output projection — R6-verified 2-barrier gl_lds staging.
// ---------------------------------------------------------------------------
__global__ __launch_bounds__(256) void out_mfma_kernel(
    const ushort_t* __restrict__ attb,  // [4096,1024] bf16
    const ushort_t* __restrict__ Wob,   // [1024,1024] bf16
    float* __restrict__ out)            // [4096,1024] fp32
{
    __shared__ ushort_t As[128 * 32];   // [m][k] unpadded
    __shared__ ushort_t Bs[128 * 32];   // [n][k]

    const int tid = threadIdx.x;
    const int w = tid >> 6, lane = tid & 63;
    const int lm = lane & 15, g = lane >> 4, lk8 = g * 8;
    const int wm = (w >> 1) * 64, wn = (w & 1) * 64;
    const int m0 = blockIdx.y * 128, n0 = blockIdx.x * 128;

    const int lrow = lane >> 2;
    const int lcol8 = (lane & 3) * 8;

    v4f acc[4][4] = {};

    for (int k0 = 0; k0 < DMODEL; k0 += 32) {
        __syncthreads();
#pragma unroll
        for (int j = 0; j < 2; ++j) {
            const int rA = w * 32 + j * 16;
            gl_lds16(&attb[(size_t)(m0 + rA + lrow) * DMODEL + k0 + lcol8], &As[rA * 32]);
            gl_lds16(&Wob [(size_t)(n0 + rA + lrow) * DMODEL + k0 + lcol8], &Bs[rA * 32]);
        }
        __syncthreads();

        short8 af[4], bfr[4];
#pragma unroll
        for (int mf = 0; mf < 4; ++mf) af[mf]  = *reinterpret_cast<const short8*>(&As[(wm + mf * 16 + lm) * 32 + lk8]);
#pragma unroll
        for (int nf = 0; nf < 4; ++nf) bfr[nf] = *reinterpret_cast<const short8*>(&Bs[(wn + nf * 16 + lm) * 32 + lk8]);
#pragma unroll
        for (int mf = 0; mf < 4; ++mf)
#pragma unroll
            for (int nf = 0; nf < 4; ++nf)
                acc[mf][nf] = __builtin_amdgcn_mfma_f32_16x16x32_bf16(af[mf], bfr[nf], acc[mf][nf], 0, 0, 0);
    }

#pragma unroll
    for (int mf = 0; mf < 4; ++mf)
#pragma unroll
        for (int reg = 0; reg < 4; ++reg) {
            const int m = m0 + wm + mf * 16 + g * 4 + reg;
#pragma unroll
            for (int nf = 0; nf < 4; ++nf) {
                const int n = n0 + wn + nf * 16 + lm;
                out[(size_t)m * DMODEL + n] = acc[mf][nf][reg];
            }
        }
}

// ---------------------------------------------------------------------------
extern "C" void kernel_launch(void* const* d_in, const int* in_sizes, int n_in,
                              void* d_out, int out_size, void* d_ws, size_t ws_size,
                              hipStream_t stream) {
    (void)in_sizes; (void)n_in; (void)out_size; (void)ws_size;

    const float* x    = (const float*)d_in[0];
    const float* Wa   = (const float*)d_in[1];
    const float* Wo   = (const float*)d_in[2];
    const float* rope = (const float*)d_in[3];
    const int*   tp   = (const int*)d_in[4];
    float* out = (float*)d_out;

    char* ws = (char*)d_ws;
    ushort_t* xb   = (ushort_t*)(ws);                       // 8 MB
    ushort_t* Wab  = (ushort_t*)(ws + (8u << 20));          // 6 MB
    ushort_t* Wob  = (ushort_t*)(ws + (14u << 20));         // 2 MB
    float*    cosT = (float*)   (ws + (16u << 20));         // 0.5 MB
    float*    sinT = (float*)   (ws + (16u << 20) + (512u << 10));
    ushort_t* Qb   = (ushort_t*)(ws + (17u << 20));         // 8 MB
    ushort_t* Kb   = (ushort_t*)(ws + (25u << 20));         // 8 MB
    ushort_t* Vb   = (ushort_t*)(ws + (33u << 20));         // 8 MB
    ushort_t* Vtb  = (ushort_t*)(ws + (41u << 20));         // 8 MB
    ushort_t* attb = (ushort_t*)(ws + (49u << 20));         // 8 MB

    dim3 blk(256);
    prep_kernel<<<dim3(8704), blk, 0, stream>>>(x, Wa, Wo, rope, xb, Wab, Wob, cosT, sinT);

    const size_t qkv_lds = 128 * ES_STRIDE * sizeof(ushort_t);  // 34816 B
    qkv_mfma_kernel<<<dim3(NQKV / 128, M_ROWS / 128), blk, qkv_lds, stream>>>(
        xb, Wab, cosT, sinT, tp, Qb, Kb, Vb);
    transpose_v_kernel<<<dim3(SEQ / 64, B_SZ * NH), blk, 0, stream>>>(Vb, Vtb);
    attn_mfma_kernel<<<dim3(16, NH, B_SZ), blk, 0, stream>>>(Qb, Kb, Vtb, attb);
    out_mfma_kernel<<<dim3(DMODEL / 128, M_ROWS / 128), blk, 0, stream>>>(attb, Wob, out);
}